// Round 1
// baseline (313.989 us; speedup 1.0000x reference)
//
#include <hip/hip_runtime.h>

// BertCRF: emissions = hidden @ cls_w + cls_b ; CRF NLL (num - logZ), loss = -mean
// B=64 S=512 H=768 L=9
#define BB 64
#define SS 512
#define HH 768
#define LL 9
#define NROWS (BB * SS)

// ---------------------------------------------------------------------------
// Kernel 1: emissions GEMM. One wave per row (grid-stride). K=768 = 64 lanes
// x 12 floats (3 float4, stride 256 floats). Weight col-slices cached in
// registers (108 regs/lane, loaded once). 9 dot products reduced with a
// 6-step shfl_xor butterfly. Memory-bound on the 96MB hidden read.
// ---------------------------------------------------------------------------
__global__ __launch_bounds__(256) void emis_gemm(
    const float* __restrict__ hidden, const float* __restrict__ w,
    const float* __restrict__ bias, float* __restrict__ emis) {
  const int lane = threadIdx.x & 63;
  const int wid = blockIdx.x * (blockDim.x >> 6) + (threadIdx.x >> 6);
  const int nw = gridDim.x * (blockDim.x >> 6);

  // per-lane weight cache: k = lane*4 + 256*kk + e
  float W[3][4][LL];
#pragma unroll
  for (int kk = 0; kk < 3; ++kk) {
    const int kbase = lane * 4 + 256 * kk;
#pragma unroll
    for (int e = 0; e < 4; ++e)
#pragma unroll
      for (int j = 0; j < LL; ++j)
        W[kk][e][j] = w[(kbase + e) * LL + j];
  }
  const float bias_lane = (lane < LL) ? bias[lane] : 0.f;

  for (int row = wid; row < NROWS; row += nw) {
    const float4* hp = reinterpret_cast<const float4*>(hidden + (size_t)row * HH);
    const float4 h0 = hp[lane];
    const float4 h1 = hp[lane + 64];
    const float4 h2 = hp[lane + 128];
    float acc[LL];
#pragma unroll
    for (int j = 0; j < LL; ++j) {
      acc[j] = h0.x * W[0][0][j] + h0.y * W[0][1][j] + h0.z * W[0][2][j] + h0.w * W[0][3][j]
             + h1.x * W[1][0][j] + h1.y * W[1][1][j] + h1.z * W[1][2][j] + h1.w * W[1][3][j]
             + h2.x * W[2][0][j] + h2.y * W[2][1][j] + h2.z * W[2][2][j] + h2.w * W[2][3][j];
    }
#pragma unroll
    for (int off = 32; off; off >>= 1)
#pragma unroll
      for (int j = 0; j < LL; ++j) acc[j] += __shfl_xor(acc[j], off);
    // lane < 9 writes element j=lane; select acc[lane] without dynamic indexing
    float v = acc[0];
#pragma unroll
    for (int j = 1; j < LL; ++j) v = (lane == j) ? acc[j] : v;
    if (lane < LL) emis[(size_t)row * LL + lane] = v + bias_lane;
  }
}

// ---------------------------------------------------------------------------
// Kernel 2: per-batch CRF. One 64-thread block per batch.
// Phase A: numerator, wave-parallel over timesteps + butterfly reduce.
// Phase B: forward recursion, lane j (j<9) owns state j; 9 shfl broadcasts
// per step; base-2 logsumexp with max subtraction. mask handled generally.
// ---------------------------------------------------------------------------
__global__ __launch_bounds__(64) void crf_scan(
    const float* __restrict__ emis, const int* __restrict__ labels,
    const int* __restrict__ msk, const float* __restrict__ startT,
    const float* __restrict__ endT, const float* __restrict__ trans,
    float* __restrict__ llh) {
  const int b = blockIdx.x;
  const int lane = threadIdx.x;
  const float* __restrict__ emb = emis + (size_t)b * SS * LL;
  const int* __restrict__ lab = labels + b * SS;
  const int* __restrict__ mk = msk + b * SS;

  // ---- numerator ----
  float acc = 0.f;
  int msum = 0;
  for (int t = lane; t < SS; t += 64) {
    int tg = lab[t]; if (tg == -100) tg = 0;
    const int mt = mk[t];
    msum += mt;
    if (t == 0) {
      acc += startT[tg] + emb[tg];
    } else {
      int tp = lab[t - 1]; if (tp == -100) tp = 0;
      acc += (trans[tp * LL + tg] + emb[t * LL + tg]) * (float)mt;
    }
  }
#pragma unroll
  for (int off = 32; off; off >>= 1) {
    acc += __shfl_xor(acc, off);
    msum += __shfl_xor(msum, off);
  }
  const int seq_end = msum - 1;
  int lt = lab[seq_end]; if (lt == -100) lt = 0;
  const float num = acc + endT[lt];

  // ---- forward recursion (denominator) ----
  const int j = (lane < LL) ? lane : (LL - 1);  // lanes 9..63 duplicate state 8
  float Tc[LL];
#pragma unroll
  for (int i = 0; i < LL; ++i) Tc[i] = trans[i * LL + j];
  const float L2E = 1.4426950408889634f;
  const float LN2 = 0.6931471805599453f;

  float s = startT[j] + emb[j];
  for (int t = 1; t < SS; ++t) {
    const float emj = emb[t * LL + j];
    const int mt = mk[t];
    const float s0 = __shfl(s, 0), s1 = __shfl(s, 1), s2 = __shfl(s, 2);
    const float s3 = __shfl(s, 3), s4 = __shfl(s, 4), s5 = __shfl(s, 5);
    const float s6 = __shfl(s, 6), s7 = __shfl(s, 7), s8 = __shfl(s, 8);
    const float a0 = s0 + Tc[0], a1 = s1 + Tc[1], a2 = s2 + Tc[2];
    const float a3 = s3 + Tc[3], a4 = s4 + Tc[4], a5 = s5 + Tc[5];
    const float a6 = s6 + Tc[6], a7 = s7 + Tc[7], a8 = s8 + Tc[8];
    const float m = fmaxf(fmaxf(fmaxf(fmaxf(a0, a1), fmaxf(a2, a3)),
                                fmaxf(fmaxf(a4, a5), fmaxf(a6, a7))), a8);
    const float e =
        ((exp2f((a0 - m) * L2E) + exp2f((a1 - m) * L2E)) +
         (exp2f((a2 - m) * L2E) + exp2f((a3 - m) * L2E))) +
        ((exp2f((a4 - m) * L2E) + exp2f((a5 - m) * L2E)) +
         (exp2f((a6 - m) * L2E) + exp2f((a7 - m) * L2E))) +
        exp2f((a8 - m) * L2E);
    const float snew = m + LN2 * log2f(e) + emj;
    s = mt ? snew : s;
  }
  s += endT[j];
  {
    const float s0 = __shfl(s, 0), s1 = __shfl(s, 1), s2 = __shfl(s, 2);
    const float s3 = __shfl(s, 3), s4 = __shfl(s, 4), s5 = __shfl(s, 5);
    const float s6 = __shfl(s, 6), s7 = __shfl(s, 7), s8 = __shfl(s, 8);
    const float m = fmaxf(fmaxf(fmaxf(fmaxf(s0, s1), fmaxf(s2, s3)),
                                fmaxf(fmaxf(s4, s5), fmaxf(s6, s7))), s8);
    const float e =
        ((exp2f((s0 - m) * L2E) + exp2f((s1 - m) * L2E)) +
         (exp2f((s2 - m) * L2E) + exp2f((s3 - m) * L2E))) +
        ((exp2f((s4 - m) * L2E) + exp2f((s5 - m) * L2E)) +
         (exp2f((s6 - m) * L2E) + exp2f((s7 - m) * L2E))) +
        exp2f((s8 - m) * L2E);
    const float denom = m + LN2 * log2f(e);
    if (lane == 0) llh[b] = num - denom;
  }
}

// ---------------------------------------------------------------------------
// Kernel 3: loss = -mean(llh)
// ---------------------------------------------------------------------------
__global__ __launch_bounds__(64) void finalize(const float* __restrict__ llh,
                                               float* __restrict__ out) {
  float v = llh[threadIdx.x];
#pragma unroll
  for (int off = 32; off; off >>= 1) v += __shfl_xor(v, off);
  if (threadIdx.x == 0) out[0] = -v * (1.0f / BB);
}

extern "C" void kernel_launch(void* const* d_in, const int* in_sizes, int n_in,
                              void* d_out, int out_size, void* d_ws, size_t ws_size,
                              hipStream_t stream) {
  const float* hidden = (const float*)d_in[0];
  const float* cls_w  = (const float*)d_in[1];
  const float* cls_b  = (const float*)d_in[2];
  const float* startT = (const float*)d_in[3];
  const float* endT   = (const float*)d_in[4];
  const float* trans  = (const float*)d_in[5];
  const int* labels   = (const int*)d_in[6];
  const int* amask    = (const int*)d_in[7];

  float* out = (float*)d_out;
  float* emis = out + 1;        // output layout: [loss][emissions B*S*L]
  float* llh = (float*)d_ws;    // 64 floats scratch

  emis_gemm<<<512, 256, 0, stream>>>(hidden, cls_w, cls_b, emis);
  crf_scan<<<BB, 64, 0, stream>>>(emis, labels, amask, startT, endT, trans, llh);
  finalize<<<1, 64, 0, stream>>>(llh, out);
}

// Round 3
// 197.934 us; speedup vs baseline: 1.5863x; 1.5863x over previous
//
#include <hip/hip_runtime.h>

// BertCRF: emissions = hidden @ cls_w + cls_b ; CRF NLL (num - logZ), loss = -mean
// B=64 S=512 H=768 L=9
#define BB 64
#define SS 512
#define HH 768
#define LL 9
#define NROWS (BB * SS)
#define NCHUNK 16
#define CLEN 32   // SS / NCHUNK

#define L2E 1.4426950408889634f
#define LN2 0.6931471805599453f
#define NEGINF (-1e30f)

// ---------------------------------------------------------------------------
// Kernel 1: emissions GEMM. Block=256 (4 waves), 8 rows per iteration
// (2 rows/wave). K=768 split over 64 lanes (12 floats each); W cached in
// 108 registers/lane (iteration-invariant). Reduction via two-stage LDS
// (no shuffle butterfly): partials [8][65][12] (padded, ~conflict-free),
// then 72 threads each sum 64 partials and store contiguously.
// ---------------------------------------------------------------------------
__global__ __launch_bounds__(256, 2) void emis_gemm(
    const float* __restrict__ hidden, const float* __restrict__ w,
    const float* __restrict__ bias, float* __restrict__ emis) {
  __shared__ float part[8][65][12];
  const int tid = threadIdx.x;
  const int lane = tid & 63;
  const int wv = tid >> 6;  // 0..3

  // per-lane weight cache: k = lane*4 + 256*kk + e
  float W[3][4][LL];
#pragma unroll
  for (int kk = 0; kk < 3; ++kk) {
    const int kbase = lane * 4 + 256 * kk;
#pragma unroll
    for (int e = 0; e < 4; ++e)
#pragma unroll
      for (int j = 0; j < LL; ++j)
        W[kk][e][j] = w[(kbase + e) * LL + j];
  }
  const int rr = tid / 9, jj = tid - rr * 9;  // reduce-phase mapping (tid<72)
  const float bj = (tid < 72) ? bias[jj] : 0.f;

  const int r0 = wv * 2, r1 = r0 + 1;
  for (int g = blockIdx.x; g < NROWS / 8; g += gridDim.x) {
    const int rowbase = g * 8;
    const float4* hA = reinterpret_cast<const float4*>(hidden + (size_t)(rowbase + r0) * HH);
    const float4* hB = reinterpret_cast<const float4*>(hidden + (size_t)(rowbase + r1) * HH);
    const float4 a0 = hA[lane], a1 = hA[lane + 64], a2 = hA[lane + 128];
    const float4 b0 = hB[lane], b1 = hB[lane + 64], b2 = hB[lane + 128];
    float acc0[LL], acc1[LL];
#pragma unroll
    for (int j = 0; j < LL; ++j) {
      acc0[j] = a0.x * W[0][0][j] + a0.y * W[0][1][j] + a0.z * W[0][2][j] + a0.w * W[0][3][j]
              + a1.x * W[1][0][j] + a1.y * W[1][1][j] + a1.z * W[1][2][j] + a1.w * W[1][3][j]
              + a2.x * W[2][0][j] + a2.y * W[2][1][j] + a2.z * W[2][2][j] + a2.w * W[2][3][j];
      acc1[j] = b0.x * W[0][0][j] + b0.y * W[0][1][j] + b0.z * W[0][2][j] + b0.w * W[0][3][j]
              + b1.x * W[1][0][j] + b1.y * W[1][1][j] + b1.z * W[1][2][j] + b1.w * W[1][3][j]
              + b2.x * W[2][0][j] + b2.y * W[2][1][j] + b2.z * W[2][2][j] + b2.w * W[2][3][j];
    }
    // write partials (16B-aligned: stride 12 floats = 48B)
    float4* p0 = reinterpret_cast<float4*>(&part[r0][lane][0]);
    p0[0] = make_float4(acc0[0], acc0[1], acc0[2], acc0[3]);
    p0[1] = make_float4(acc0[4], acc0[5], acc0[6], acc0[7]);
    part[r0][lane][8] = acc0[8];
    float4* p1 = reinterpret_cast<float4*>(&part[r1][lane][0]);
    p1[0] = make_float4(acc1[0], acc1[1], acc1[2], acc1[3]);
    p1[1] = make_float4(acc1[4], acc1[5], acc1[6], acc1[7]);
    part[r1][lane][8] = acc1[8];
    __syncthreads();
    if (tid < 72) {
      float s0 = 0.f, s1 = 0.f, s2 = 0.f, s3 = 0.f;
#pragma unroll
      for (int l = 0; l < 64; l += 4) {
        s0 += part[rr][l + 0][jj];
        s1 += part[rr][l + 1][jj];
        s2 += part[rr][l + 2][jj];
        s3 += part[rr][l + 3][jj];
      }
      emis[(size_t)(rowbase + rr) * LL + jj] = (s0 + s1) + (s2 + s3) + bj;
    }
    __syncthreads();
  }
}

// ---------------------------------------------------------------------------
// Kernel 2: CRF chunk scan (stage 1). Grid = 64 batches x 16 chunks.
// Block = 128 threads (2 waves). Chunk 0: run the real alpha recursion for
// steps 1..31 from init = start + em[0]. Chunks c>0: compute the 9x9
// log-matrix product of steps [32c, 32c+32) via 9 basis-row recursions.
// Wave 0 holds rows 0..6 (lanes r*9+j), wave 1 rows 7..8 (lanes 0..17).
// Masked step == identity (s unchanged), matching the reference's
// where(mask, next, prev) on both the alpha vector and matrix rows.
// ---------------------------------------------------------------------------
__global__ __launch_bounds__(128) void crf_chunk(
    const float* __restrict__ emis, const int* __restrict__ msk,
    const float* __restrict__ startT, const float* __restrict__ trans,
    float* __restrict__ initv, float* __restrict__ Pmat) {
  __shared__ float em_lds[CLEN * LL];
  __shared__ int mk_lds[CLEN];
  const int b = blockIdx.x >> 4;
  const int c = blockIdx.x & 15;
  const int tid = threadIdx.x;
  const int lane = tid & 63;
  const int wid = tid >> 6;

  const float* src = emis + ((size_t)b * SS + c * CLEN) * LL;
  for (int i = tid; i < CLEN * LL; i += 128) em_lds[i] = src[i];
  for (int i = tid; i < CLEN; i += 128) mk_lds[i] = msk[b * SS + c * CLEN + i];
  __syncthreads();

  int rloc = lane / 9;
  int j = lane - rloc * 9;
  if (rloc > 6) { rloc = 6; j = 8; }  // lane 63 (inactive) kept in-bounds
  const int rbase = rloc * 9;
  const bool active = (wid == 0) ? (lane < 63) : (lane < 18);
  const int r = wid * 7 + rloc;  // global row this lane-group computes

  float Tc[LL];
#pragma unroll
  for (int i = 0; i < LL; ++i) Tc[i] = trans[i * LL + j];

  float s;
  if (c == 0) s = startT[j] + em_lds[j];
  else s = (j == r) ? 0.f : NEGINF;
  const int t0 = (c == 0) ? 1 : 0;

  for (int t = t0; t < CLEN; ++t) {
    const float emj = em_lds[t * LL + j];
    const int mt = mk_lds[t];
    const float s0 = __shfl(s, rbase + 0), s1 = __shfl(s, rbase + 1), s2 = __shfl(s, rbase + 2);
    const float s3 = __shfl(s, rbase + 3), s4 = __shfl(s, rbase + 4), s5 = __shfl(s, rbase + 5);
    const float s6 = __shfl(s, rbase + 6), s7 = __shfl(s, rbase + 7), s8 = __shfl(s, rbase + 8);
    const float a0 = s0 + Tc[0], a1 = s1 + Tc[1], a2 = s2 + Tc[2];
    const float a3 = s3 + Tc[3], a4 = s4 + Tc[4], a5 = s5 + Tc[5];
    const float a6 = s6 + Tc[6], a7 = s7 + Tc[7], a8 = s8 + Tc[8];
    const float m = fmaxf(fmaxf(fmaxf(fmaxf(a0, a1), fmaxf(a2, a3)),
                                fmaxf(fmaxf(a4, a5), fmaxf(a6, a7))), a8);
    const float e =
        ((exp2f((a0 - m) * L2E) + exp2f((a1 - m) * L2E)) +
         (exp2f((a2 - m) * L2E) + exp2f((a3 - m) * L2E))) +
        ((exp2f((a4 - m) * L2E) + exp2f((a5 - m) * L2E)) +
         (exp2f((a6 - m) * L2E) + exp2f((a7 - m) * L2E))) +
        exp2f((a8 - m) * L2E);
    const float snew = m + LN2 * log2f(e) + emj;
    s = mt ? snew : s;
  }

  if (active) {
    if (c == 0) {
      if (wid == 0 && lane < LL) initv[b * LL + j] = s;
    } else {
      Pmat[((size_t)b * NCHUNK + c) * 81 + r * LL + j] = s;
    }
  }
}

// ---------------------------------------------------------------------------
// Kernel 3: per-batch combine (stage 2) + numerator. One 64-thread block
// per batch. Numerator: wave-parallel over timesteps + butterfly reduce.
// Denominator: alpha = initv, then 15 sequential vector x log-matrix
// combines (P staged in LDS), then lse with end transitions.
// ---------------------------------------------------------------------------
__global__ __launch_bounds__(64) void crf_combine(
    const float* __restrict__ emis, const int* __restrict__ labels,
    const int* __restrict__ msk, const float* __restrict__ startT,
    const float* __restrict__ endT, const float* __restrict__ trans,
    const float* __restrict__ initv, const float* __restrict__ Pmat,
    float* __restrict__ llh) {
  __shared__ float Pl[15 * 81];
  const int b = blockIdx.x;
  const int lane = threadIdx.x;
  const float* __restrict__ emb = emis + (size_t)b * SS * LL;
  const int* __restrict__ lab = labels + b * SS;
  const int* __restrict__ mk = msk + b * SS;

  const float* Pb = Pmat + (size_t)b * NCHUNK * 81 + 81;
  for (int i = lane; i < 15 * 81; i += 64) Pl[i] = Pb[i];

  // ---- numerator ----
  float acc = 0.f;
  int msum = 0;
  for (int t = lane; t < SS; t += 64) {
    int tg = lab[t]; if (tg == -100) tg = 0;
    const int mt = mk[t];
    msum += mt;
    if (t == 0) {
      acc += startT[tg] + emb[tg];
    } else {
      int tp = lab[t - 1]; if (tp == -100) tp = 0;
      acc += (trans[tp * LL + tg] + emb[t * LL + tg]) * (float)mt;
    }
  }
#pragma unroll
  for (int off = 32; off; off >>= 1) {
    acc += __shfl_xor(acc, off);
    msum += __shfl_xor(msum, off);
  }
  const int seq_end = msum - 1;
  int lt = lab[seq_end]; if (lt == -100) lt = 0;
  const float num = acc + endT[lt];

  __syncthreads();

  // ---- denominator ----
  const int j = (lane < LL) ? lane : 8;
  float a = initv[b * LL + j];
#pragma unroll 1
  for (int c = 0; c < 15; ++c) {
    const float* P = &Pl[c * 81];
    const float s0 = __shfl(a, 0), s1 = __shfl(a, 1), s2 = __shfl(a, 2);
    const float s3 = __shfl(a, 3), s4 = __shfl(a, 4), s5 = __shfl(a, 5);
    const float s6 = __shfl(a, 6), s7 = __shfl(a, 7), s8 = __shfl(a, 8);
    const float a0 = s0 + P[0 * LL + j], a1 = s1 + P[1 * LL + j], a2 = s2 + P[2 * LL + j];
    const float a3 = s3 + P[3 * LL + j], a4 = s4 + P[4 * LL + j], a5 = s5 + P[5 * LL + j];
    const float a6 = s6 + P[6 * LL + j], a7 = s7 + P[7 * LL + j], a8 = s8 + P[8 * LL + j];
    const float m = fmaxf(fmaxf(fmaxf(fmaxf(a0, a1), fmaxf(a2, a3)),
                                fmaxf(fmaxf(a4, a5), fmaxf(a6, a7))), a8);
    const float e =
        ((exp2f((a0 - m) * L2E) + exp2f((a1 - m) * L2E)) +
         (exp2f((a2 - m) * L2E) + exp2f((a3 - m) * L2E))) +
        ((exp2f((a4 - m) * L2E) + exp2f((a5 - m) * L2E)) +
         (exp2f((a6 - m) * L2E) + exp2f((a7 - m) * L2E))) +
        exp2f((a8 - m) * L2E);
    a = m + LN2 * log2f(e);
  }
  a += endT[j];
  {
    const float s0 = __shfl(a, 0), s1 = __shfl(a, 1), s2 = __shfl(a, 2);
    const float s3 = __shfl(a, 3), s4 = __shfl(a, 4), s5 = __shfl(a, 5);
    const float s6 = __shfl(a, 6), s7 = __shfl(a, 7), s8 = __shfl(a, 8);
    const float m = fmaxf(fmaxf(fmaxf(fmaxf(s0, s1), fmaxf(s2, s3)),
                                fmaxf(fmaxf(s4, s5), fmaxf(s6, s7))), s8);
    const float e =
        ((exp2f((s0 - m) * L2E) + exp2f((s1 - m) * L2E)) +
         (exp2f((s2 - m) * L2E) + exp2f((s3 - m) * L2E))) +
        ((exp2f((s4 - m) * L2E) + exp2f((s5 - m) * L2E)) +
         (exp2f((s6 - m) * L2E) + exp2f((s7 - m) * L2E))) +
        exp2f((s8 - m) * L2E);
    const float denom = m + LN2 * log2f(e);
    if (lane == 0) llh[b] = num - denom;
  }
}

// ---------------------------------------------------------------------------
// Kernel 4: loss = -mean(llh)
// ---------------------------------------------------------------------------
__global__ __launch_bounds__(64) void finalize(const float* __restrict__ llh,
                                               float* __restrict__ out) {
  float v = llh[threadIdx.x];
#pragma unroll
  for (int off = 32; off; off >>= 1) v += __shfl_xor(v, off);
  if (threadIdx.x == 0) out[0] = -v * (1.0f / BB);
}

extern "C" void kernel_launch(void* const* d_in, const int* in_sizes, int n_in,
                              void* d_out, int out_size, void* d_ws, size_t ws_size,
                              hipStream_t stream) {
  const float* hidden = (const float*)d_in[0];
  const float* cls_w  = (const float*)d_in[1];
  const float* cls_b  = (const float*)d_in[2];
  const float* startT = (const float*)d_in[3];
  const float* endT   = (const float*)d_in[4];
  const float* trans  = (const float*)d_in[5];
  const int* labels   = (const int*)d_in[6];
  const int* amask    = (const int*)d_in[7];

  float* out = (float*)d_out;
  float* emis = out + 1;  // output layout: [loss][emissions B*S*L]

  float* llh = (float*)d_ws;            // 64
  float* initv = llh + 64;              // 64*9
  float* Pmat = initv + 64 * LL;        // 64*16*81

  emis_gemm<<<1024, 256, 0, stream>>>(hidden, cls_w, cls_b, emis);
  crf_chunk<<<BB * NCHUNK, 128, 0, stream>>>(emis, amask, startT, trans, initv, Pmat);
  crf_combine<<<BB, 64, 0, stream>>>(emis, labels, amask, startT, endT, trans, initv, Pmat, llh);
  finalize<<<1, 64, 0, stream>>>(llh, out);
}